// Round 16
// baseline (1618.291 us; speedup 1.0000x reference)
//
#include <hip/hip_runtime.h>
#include <hip/hip_bf16.h>

typedef unsigned short u16;
typedef unsigned int   u32;

#define BB    64
#define PP    196
#define ENC   2048
#define DEC   512
#define ATT   512
#define EMB   512
#define VOCAB 10000
#define VPAD2 10112   // W_out padded rows (79 * 128)
#define TT    19
#define LCAP  20
#define XDIM  3072    // [e_t(512) | gated_ctx(2048) | h(512)]
#define LDSTR 40      // LDS row stride (32 + 8 pad) for BK=32 kernels
#define LD64  72      // LDS row stride (64 + 8 pad) for BK=64 ping-pong kernels

typedef __bf16 bf16x8 __attribute__((ext_vector_type(8)));
typedef float  f32x4  __attribute__((ext_vector_type(4)));

__device__ __forceinline__ float bf2f(u16 u) {
  union { float f; u32 i; } v; v.i = ((u32)u) << 16; return v.f;
}
__device__ __forceinline__ u16 f2bf(float f) {
  u32 x = __float_as_uint(f);
  u32 r = (x + 0x7FFFu + ((x >> 16) & 1u)) >> 16;
  return (u16)r;
}
__device__ __forceinline__ u32 pack2(float a, float b) {
  return (u32)f2bf(a) | ((u32)f2bf(b) << 16);
}
__device__ __forceinline__ float wred_sum(float v) {
  #pragma unroll
  for (int off = 32; off > 0; off >>= 1) v += __shfl_xor(v, off, 64);
  return v;
}
__device__ __forceinline__ float wred_max(float v) {
  #pragma unroll
  for (int off = 32; off > 0; off >>= 1) v = fmaxf(v, __shfl_xor(v, off, 64));
  return v;
}
__device__ __forceinline__ float tanh_fast(float x) {
  return 1.f - 2.f / (__expf(2.f * x) + 1.f);
}
__device__ __forceinline__ float sigm(float x) {
  return 1.f / (1.f + __expf(-x));
}

// ---------------- CVT: f32 -> bf16 ----------------
__global__ __launch_bounds__(256) void k_cvt_simple(u16* __restrict__ dst,
    const float* __restrict__ src, int n4) {
  int stride = gridDim.x * blockDim.x;
  for (int i = blockIdx.x * blockDim.x + threadIdx.x; i < n4; i += stride) {
    float4 v = ((const float4*)src)[i];
    ((uint2*)dst)[i] = make_uint2(pack2(v.x, v.y), pack2(v.z, v.w));
  }
}

// W_out (10000x512) -> bf16 padded to 10112 rows (pad rows = 0)
__global__ __launch_bounds__(256) void k_cvt_pad(u16* __restrict__ dst,
    const float* __restrict__ src) {
  int total = VPAD2 * (DEC / 2);
  int stride = gridDim.x * blockDim.x;
  for (int i = blockIdx.x * blockDim.x + threadIdx.x; i < total; i += stride) {
    int row = i >> 8, c2 = i & 255;
    u32 v = 0;
    if (row < VOCAB) {
      float2 f = ((const float2*)src)[(size_t)row * 256 + c2];
      v = pack2(f.x, f.y);
    }
    ((u32*)dst)[i] = v;
  }
}

// Wcomb[2048][3072] = [W_ih (2048x2560) | W_hh (2048x512)] -> bf16
__global__ __launch_bounds__(256) void k_cvt_comb(u16* __restrict__ dst,
    const float* __restrict__ Wih, const float* __restrict__ Whh) {
  int j = blockIdx.x;
  for (int t = threadIdx.x; t < 768; t += 256) {
    int col = t * 4;
    float4 v = (col < 2560)
        ? ((const float4*)(Wih + (size_t)j * 2560))[t]
        : ((const float4*)(Whh + (size_t)j * 512))[(col - 2560) >> 2];
    ((uint2*)(dst + (size_t)j * XDIM))[t] = make_uint2(pack2(v.x, v.y), pack2(v.z, v.w));
  }
}

// ---------------- P0a: avgb = mean_p img -> bf16 (reads imgb when available) ----------------
template <int SRC>
__global__ __launch_bounds__(256) void k_avg(const u16* __restrict__ imgb,
    const float* __restrict__ imgf, u16* __restrict__ avgb) {
  int b = blockIdx.x;
  int col = blockIdx.y * 256 + threadIdx.x;
  float s = 0.f;
  if (SRC == 0) {
    const u16* base = imgb + (size_t)b * PP * ENC + col;
    for (int p = 0; p < PP; ++p) s += bf2f(base[(size_t)p * ENC]);
  } else {
    const float* base = imgf + (size_t)b * PP * ENC + col;
    for (int p = 0; p < PP; ++p) s += base[(size_t)p * ENC];
  }
  avgb[b * ENC + col] = f2bf(s * (1.f / PP));
}

// ---------------- P0b: [h0|c0] = tanh(avg @ [Wh;Wc]^T + b)  (MFMA, N=1024, K=2048) ----------------
__global__ __launch_bounds__(256) void k_init_mfma(const u16* __restrict__ avgb,
    const u16* __restrict__ Winitb, const float* __restrict__ bh,
    const float* __restrict__ bc, u16* __restrict__ h, float* __restrict__ c) {
  __shared__ __align__(16) u16 As[2 * 64 * LD64];
  __shared__ __align__(16) u16 Bs[2 * 64 * LD64];
  int n0 = blockIdx.x * 64;
  int tid = threadIdx.x, wv = tid >> 6, lane = tid & 63;
  int wm = wv >> 1, wn = wv & 1;
  int fr = lane & 15, kg = (lane >> 4) * 8, rq = lane >> 4;
  int r0 = tid >> 3, kc0 = (tid & 7) * 8;
  int r1 = (tid + 256) >> 3, kc1 = ((tid + 256) & 7) * 8;
  uint4 pa0 = *(const uint4*)&avgb[(size_t)r0 * ENC + kc0];
  uint4 pa1 = *(const uint4*)&avgb[(size_t)r1 * ENC + kc1];
  uint4 pb0 = *(const uint4*)&Winitb[(size_t)(n0 + r0) * ENC + kc0];
  uint4 pb1 = *(const uint4*)&Winitb[(size_t)(n0 + r1) * ENC + kc1];
  f32x4 acc[2][2] = {};
  const int NK = ENC / 64;  // 32
  for (int kt = 0; kt < NK; ++kt) {
    u16* as = As + (kt & 1) * (64 * LD64);
    u16* bs = Bs + (kt & 1) * (64 * LD64);
    *(uint4*)&as[r0 * LD64 + kc0] = pa0;
    *(uint4*)&as[r1 * LD64 + kc1] = pa1;
    *(uint4*)&bs[r0 * LD64 + kc0] = pb0;
    *(uint4*)&bs[r1 * LD64 + kc1] = pb1;
    __syncthreads();
    if (kt + 1 < NK) {
      int k0 = (kt + 1) * 64;
      pa0 = *(const uint4*)&avgb[(size_t)r0 * ENC + k0 + kc0];
      pa1 = *(const uint4*)&avgb[(size_t)r1 * ENC + k0 + kc1];
      pb0 = *(const uint4*)&Winitb[(size_t)(n0 + r0) * ENC + k0 + kc0];
      pb1 = *(const uint4*)&Winitb[(size_t)(n0 + r1) * ENC + k0 + kc1];
    }
    #pragma unroll
    for (int ks = 0; ks < 2; ++ks) {
      bf16x8 a0 = *(const bf16x8*)&as[(wm * 32 + fr) * LD64 + ks * 32 + kg];
      bf16x8 a1 = *(const bf16x8*)&as[(wm * 32 + 16 + fr) * LD64 + ks * 32 + kg];
      bf16x8 b0 = *(const bf16x8*)&bs[(wn * 32 + fr) * LD64 + ks * 32 + kg];
      bf16x8 b1 = *(const bf16x8*)&bs[(wn * 32 + 16 + fr) * LD64 + ks * 32 + kg];
      acc[0][0] = __builtin_amdgcn_mfma_f32_16x16x32_bf16(a0, b0, acc[0][0], 0, 0, 0);
      acc[0][1] = __builtin_amdgcn_mfma_f32_16x16x32_bf16(a0, b1, acc[0][1], 0, 0, 0);
      acc[1][0] = __builtin_amdgcn_mfma_f32_16x16x32_bf16(a1, b0, acc[1][0], 0, 0, 0);
      acc[1][1] = __builtin_amdgcn_mfma_f32_16x16x32_bf16(a1, b1, acc[1][1], 0, 0, 0);
    }
  }
  #pragma unroll
  for (int mi = 0; mi < 2; ++mi)
    for (int ni = 0; ni < 2; ++ni)
      #pragma unroll
      for (int r = 0; r < 4; ++r) {
        int m = wm * 32 + mi * 16 + rq * 4 + r;
        int n = n0 + wn * 32 + ni * 16 + fr;
        float v = acc[mi][ni][r];
        if (n < DEC) h[m * DEC + n] = f2bf(tanh_fast(v + bh[n]));
        else         c[m * DEC + (n - DEC)] = tanh_fast(v + bc[n - DEC]);
      }
}

// ---------------- P1: enc_proj = img @ W_enc^T + b_enc (128x128 tiles, BK=32) ----------------
// XCD swizzle: mt=(bid&7)+8*(bid>>5), nt=(bid>>3)&3 -> the 4 n-blocks of one m-tile share
// bid%8 (same XCD) so the A-tile is fetched into one L2 only. Grid 416, mt>=98 returns.
template <int SRC>
__global__ __launch_bounds__(256) void k_encproj(
    const u16* __restrict__ Ab, const float* __restrict__ Af,
    const u16* __restrict__ Wb, const float* __restrict__ Wf,
    const float* __restrict__ benc, u16* __restrict__ epj) {
  __shared__ __align__(16) u16 As[128 * LDSTR];
  __shared__ __align__(16) u16 Bs[128 * LDSTR];
  int bid = blockIdx.x;
  int mt = (bid & 7) + 8 * (bid >> 5);
  int nt = (bid >> 3) & 3;
  if (mt >= 98) return;
  int m0 = mt * 128, n0 = nt * 128;
  int tid = threadIdx.x, wv = tid >> 6, lane = tid & 63;
  int wm = wv >> 1, wn = wv & 1;
  int fr = lane & 15, kg = (lane >> 4) * 8, rq = lane >> 4;
  f32x4 acc[4][4] = {};
  for (int k0 = 0; k0 < ENC; k0 += 32) {
    __syncthreads();
    #pragma unroll
    for (int i = 0; i < 2; ++i) {
      int id = tid + i * 256;
      int r = id >> 2, kc = id & 3;
      if (SRC == 0) {
        *(uint4*)(&As[r * LDSTR + kc * 8]) = *(const uint4*)(&Ab[(size_t)(m0 + r) * ENC + k0 + kc * 8]);
        *(uint4*)(&Bs[r * LDSTR + kc * 8]) = *(const uint4*)(&Wb[(size_t)(n0 + r) * ENC + k0 + kc * 8]);
      } else {
        const float* asrc = &Af[(size_t)(m0 + r) * ENC + k0 + kc * 8];
        float4 f0 = ((const float4*)asrc)[0];
        float4 f1 = ((const float4*)asrc)[1];
        *(uint4*)(&As[r * LDSTR + kc * 8]) =
            make_uint4(pack2(f0.x, f0.y), pack2(f0.z, f0.w),
                       pack2(f1.x, f1.y), pack2(f1.z, f1.w));
        const float* bsrc = &Wf[(size_t)(n0 + r) * ENC + k0 + kc * 8];
        float4 g0 = ((const float4*)bsrc)[0];
        float4 g1 = ((const float4*)bsrc)[1];
        *(uint4*)(&Bs[r * LDSTR + kc * 8]) =
            make_uint4(pack2(g0.x, g0.y), pack2(g0.z, g0.w),
                       pack2(g1.x, g1.y), pack2(g1.z, g1.w));
      }
    }
    __syncthreads();
    bf16x8 af[4], bfr[4];
    #pragma unroll
    for (int i = 0; i < 4; ++i) {
      af[i]  = *(const bf16x8*)(&As[(wm * 64 + i * 16 + fr) * LDSTR + kg]);
      bfr[i] = *(const bf16x8*)(&Bs[(wn * 64 + i * 16 + fr) * LDSTR + kg]);
    }
    #pragma unroll
    for (int mi = 0; mi < 4; ++mi)
      #pragma unroll
      for (int ni = 0; ni < 4; ++ni)
        acc[mi][ni] = __builtin_amdgcn_mfma_f32_16x16x32_bf16(af[mi], bfr[ni], acc[mi][ni], 0, 0, 0);
  }
  #pragma unroll
  for (int mi = 0; mi < 4; ++mi)
    for (int ni = 0; ni < 4; ++ni)
      #pragma unroll
      for (int r = 0; r < 4; ++r) {
        int m = m0 + wm * 64 + mi * 16 + rq * 4 + r;
        int n = n0 + wn * 64 + ni * 16 + fr;
        epj[(size_t)m * ATT + n] = f2bf(acc[mi][ni][r] + benc[n]);
      }
}

// ---------------- LOGITS (end of loop, batched over all 19 steps) ----------------
__global__ __launch_bounds__(256) void k_logits(const u16* __restrict__ hall,
    const u16* __restrict__ Woutb2, const float* __restrict__ bout,
    float* __restrict__ preds) {
  __shared__ __align__(16) u16 As[128 * LDSTR];
  __shared__ __align__(16) u16 Bs[128 * LDSTR];
  int m0 = blockIdx.x * 128, n0 = blockIdx.y * 128;
  int tid = threadIdx.x, wv = tid >> 6, lane = tid & 63;
  int wm = wv >> 1, wn = wv & 1;
  int fr = lane & 15, kg = (lane >> 4) * 8, rq = lane >> 4;
  f32x4 acc[4][4] = {};
  for (int k0 = 0; k0 < DEC; k0 += 32) {
    __syncthreads();
    #pragma unroll
    for (int i = 0; i < 2; ++i) {
      int id = tid + i * 256;
      int r = id >> 2, kc = id & 3;
      *(uint4*)(&As[r * LDSTR + kc * 8]) = *(const uint4*)(&hall[(size_t)(m0 + r) * DEC + k0 + kc * 8]);
      *(uint4*)(&Bs[r * LDSTR + kc * 8]) = *(const uint4*)(&Woutb2[(size_t)(n0 + r) * DEC + k0 + kc * 8]);
    }
    __syncthreads();
    bf16x8 af[4], bfr[4];
    #pragma unroll
    for (int i = 0; i < 4; ++i) {
      af[i]  = *(const bf16x8*)(&As[(wm * 64 + i * 16 + fr) * LDSTR + kg]);
      bfr[i] = *(const bf16x8*)(&Bs[(wn * 64 + i * 16 + fr) * LDSTR + kg]);
    }
    #pragma unroll
    for (int mi = 0; mi < 4; ++mi)
      #pragma unroll
      for (int ni = 0; ni < 4; ++ni)
        acc[mi][ni] = __builtin_amdgcn_mfma_f32_16x16x32_bf16(af[mi], bfr[ni], acc[mi][ni], 0, 0, 0);
  }
  #pragma unroll
  for (int mi = 0; mi < 4; ++mi)
    for (int ni = 0; ni < 4; ++ni)
      #pragma unroll
      for (int r = 0; r < 4; ++r) {
        int m = m0 + wm * 64 + mi * 16 + rq * 4 + r;
        int n = n0 + wn * 64 + ni * 16 + fr;
        if (m < TT * BB && n < VOCAB) {
          int t = m >> 6, b = m & 63;
          preds[(size_t)b * (TT * VOCAB) + (size_t)t * VOCAB + n] = acc[mi][ni][r] + bout[n];
        }
      }
}

// ---------------- HC (critical only): U_h (8 blk) + attn-gate (32 blk); BK=64 ping-pong ----------------
__global__ __launch_bounds__(256) void k_hcons(const u16* __restrict__ h,
    const u16* __restrict__ Wdecb, const float* __restrict__ bdec,
    const u16* __restrict__ Wgateb, const float* __restrict__ bgate,
    float* __restrict__ uh, float* __restrict__ gate, u16* __restrict__ x) {
  __shared__ __align__(16) u16 As[2 * 64 * LD64];
  __shared__ __align__(16) u16 Bs[2 * 64 * LD64];
  int bid = blockIdx.x;
  int tid = threadIdx.x, wv = tid >> 6, lane = tid & 63;
  int wm = wv >> 1, wn = wv & 1;
  int fr = lane & 15, kg = (lane >> 4) * 8, rq = lane >> 4;

  if (bid == 0) {  // stage h into x[:,2560:3072] for this step's LSTM GEMM
    for (int i = tid; i < 16384; i += 256) {
      int b = i >> 8, jp = (i & 255) * 2;
      *(u32*)(&x[(size_t)b * XDIM + 2560 + jp]) = *(const u32*)(&h[b * DEC + jp]);
    }
  }

  int role, nt; const u16* Wsrc;
  if (bid < 8) { role = 0; nt = bid;     Wsrc = Wdecb;  }
  else         { role = 1; nt = bid - 8; Wsrc = Wgateb; }
  int n0 = nt * 64;

  int r0 = tid >> 3, kc0 = (tid & 7) * 8;
  int r1 = (tid + 256) >> 3, kc1 = ((tid + 256) & 7) * 8;
  uint4 pa0 = *(const uint4*)&h[(size_t)r0 * DEC + kc0];
  uint4 pa1 = *(const uint4*)&h[(size_t)r1 * DEC + kc1];
  uint4 pb0 = *(const uint4*)&Wsrc[(size_t)(n0 + r0) * DEC + kc0];
  uint4 pb1 = *(const uint4*)&Wsrc[(size_t)(n0 + r1) * DEC + kc1];
  f32x4 acc[2][2] = {};
  const int NK = DEC / 64;  // 8
  for (int kt = 0; kt < NK; ++kt) {
    u16* as = As + (kt & 1) * (64 * LD64);
    u16* bs = Bs + (kt & 1) * (64 * LD64);
    *(uint4*)&as[r0 * LD64 + kc0] = pa0;
    *(uint4*)&as[r1 * LD64 + kc1] = pa1;
    *(uint4*)&bs[r0 * LD64 + kc0] = pb0;
    *(uint4*)&bs[r1 * LD64 + kc1] = pb1;
    __syncthreads();
    if (kt + 1 < NK) {
      int k0 = (kt + 1) * 64;
      pa0 = *(const uint4*)&h[(size_t)r0 * DEC + k0 + kc0];
      pa1 = *(const uint4*)&h[(size_t)r1 * DEC + k0 + kc1];
      pb0 = *(const uint4*)&Wsrc[(size_t)(n0 + r0) * DEC + k0 + kc0];
      pb1 = *(const uint4*)&Wsrc[(size_t)(n0 + r1) * DEC + k0 + kc1];
    }
    #pragma unroll
    for (int ks = 0; ks < 2; ++ks) {
      bf16x8 a0 = *(const bf16x8*)&as[(wm * 32 + fr) * LD64 + ks * 32 + kg];
      bf16x8 a1 = *(const bf16x8*)&as[(wm * 32 + 16 + fr) * LD64 + ks * 32 + kg];
      bf16x8 b0 = *(const bf16x8*)&bs[(wn * 32 + fr) * LD64 + ks * 32 + kg];
      bf16x8 b1 = *(const bf16x8*)&bs[(wn * 32 + 16 + fr) * LD64 + ks * 32 + kg];
      acc[0][0] = __builtin_amdgcn_mfma_f32_16x16x32_bf16(a0, b0, acc[0][0], 0, 0, 0);
      acc[0][1] = __builtin_amdgcn_mfma_f32_16x16x32_bf16(a0, b1, acc[0][1], 0, 0, 0);
      acc[1][0] = __builtin_amdgcn_mfma_f32_16x16x32_bf16(a1, b0, acc[1][0], 0, 0, 0);
      acc[1][1] = __builtin_amdgcn_mfma_f32_16x16x32_bf16(a1, b1, acc[1][1], 0, 0, 0);
    }
  }
  #pragma unroll
  for (int mi = 0; mi < 2; ++mi)
    for (int ni = 0; ni < 2; ++ni)
      #pragma unroll
      for (int r = 0; r < 4; ++r) {
        int m = wm * 32 + mi * 16 + rq * 4 + r;
        int n = n0 + wn * 32 + ni * 16 + fr;
        float v = acc[mi][ni][r];
        if (role == 0) uh[m * DEC + n] = v + bdec[n];
        else           gate[m * ENC + n] = sigm(v + bgate[n]);
      }
}

// ---------------- ATT+CTX (merged): e-scores + softmax (redundant per et-block) + context ----------------
// grid (BB, 4), 256 thr. Each (b, et) block computes ALL 196 e-scores + softmax block-locally
// (identical op order in every et-block -> deterministic), then streams its 512-col context slice.
template <int SRC>
__global__ __launch_bounds__(256) void k_attctx(const float* __restrict__ uh,
    const u16* __restrict__ epj, const float* __restrict__ wfin, const float* __restrict__ bfin,
    const int* __restrict__ captions, const float* __restrict__ emb,
    const float* __restrict__ gate, const u16* __restrict__ imgb,
    const float* __restrict__ imgf,
    u16* __restrict__ x, float* __restrict__ alphas, int step) {
  __shared__ float s_uh[ATT], s_wf[ATT];
  __shared__ float s_e[PP];
  int b = blockIdx.x, et = blockIdx.y;
  int tid = threadIdx.x, w = tid >> 6, lane = tid & 63;
  for (int i = tid; i < ATT; i += 256) { s_uh[i] = uh[b * ATT + i]; s_wf[i] = wfin[i]; }
  if (et == 0) {  // e_t = emb[captions[b, step]] -> x[:, 0:512]
    int capv = captions[b * LCAP + step];
    float2 f = ((const float2*)(emb + (size_t)capv * EMB))[tid];
    ((u32*)(x + (size_t)b * XDIM))[tid] = pack2(f.x, f.y);
  }
  __syncthreads();
  // e-scores: 4 waves cover all 196 rows (49 rows/wave)
  float b0 = bfin[0];
  for (int p = w; p < PP; p += 4) {
    const u16* row = epj + (size_t)(b * PP + p) * ATT;
    float acc = 0.f;
    #pragma unroll
    for (int ki = 0; ki < 8; ++ki) {
      int a = lane + ki * 64;
      acc += tanh_fast(bf2f(row[a]) + s_uh[a]) * s_wf[a];
    }
    acc = wred_sum(acc);
    if (lane == 0) s_e[p] = acc + b0;
  }
  __syncthreads();
  if (tid < 64) {  // softmax by wave 0 (identical in every et-block)
    float v0 = s_e[tid], v1 = s_e[tid + 64], v2 = s_e[tid + 128];
    float v3 = (tid + 192 < PP) ? s_e[tid + 192] : -1e30f;
    float m = wred_max(fmaxf(fmaxf(v0, v1), fmaxf(v2, v3)));
    float e0 = __expf(v0 - m), e1 = __expf(v1 - m), e2 = __expf(v2 - m);
    float e3 = (tid + 192 < PP) ? __expf(v3 - m) : 0.f;
    float inv = 1.f / wred_sum(e0 + e1 + e2 + e3);
    s_e[tid] = e0 * inv; s_e[tid + 64] = e1 * inv; s_e[tid + 128] = e2 * inv;
    if (tid + 192 < PP) s_e[tid + 192] = e3 * inv;
  }
  __syncthreads();
  if (et == 0 && tid < PP)
    alphas[(size_t)b * (TT * PP) + (size_t)step * PP + tid] = s_e[tid];
  // context: this block's 512-col slice
  int e0i = et * 512 + tid * 2;
  float c0 = 0.f, c1 = 0.f;
  if (SRC == 0) {
    const u16* ib = imgb + (size_t)b * PP * ENC + e0i;
    for (int p = 0; p < PP; ++p) {
      u32 v = *(const u32*)(ib + (size_t)p * ENC);
      float ap = s_e[p];
      c0 += ap * bf2f((u16)(v & 0xFFFF));
      c1 += ap * bf2f((u16)(v >> 16));
    }
  } else {
    const float* ib = imgf + (size_t)b * PP * ENC + e0i;
    for (int p = 0; p < PP; ++p) {
      float2 v = *(const float2*)(ib + (size_t)p * ENC);
      float ap = s_e[p];
      c0 += ap * v.x;
      c1 += ap * v.y;
    }
  }
  float g0 = gate[b * ENC + e0i], g1 = gate[b * ENC + e0i + 1];
  *(u32*)(&x[(size_t)b * XDIM + 512 + e0i]) = pack2(c0 * g0, c1 * g1);
}

// ---------------- S3a: gates GEMM partials, K split 4 ways (BK=64 ping-pong) ----------------
__global__ __launch_bounds__(256) void k_lstm_part(const u16* __restrict__ x,
    const u16* __restrict__ Wcomb, float* __restrict__ pbuf) {
  __shared__ __align__(16) u16 As[2 * 64 * LD64];
  __shared__ __align__(16) u16 Bs[2 * 64 * LD64];
  int jt = blockIdx.x, ksp = blockIdx.y;
  int kbase = ksp * 768;
  int tid = threadIdx.x, wv = tid >> 6, lane = tid & 63;
  int wm = wv >> 1, wn = wv & 1;
  int fr = lane & 15, kg = (lane >> 4) * 8, rq = lane >> 4;
  int r0 = tid >> 3, kc0 = (tid & 7) * 8;
  int r1 = (tid + 256) >> 3, kc1 = ((tid + 256) & 7) * 8;
  int wrow0 = (r0 >> 4) * 512 + jt * 16 + (r0 & 15);
  int wrow1 = (r1 >> 4) * 512 + jt * 16 + (r1 & 15);
  uint4 pa0 = *(const uint4*)&x[(size_t)r0 * XDIM + kbase + kc0];
  uint4 pa1 = *(const uint4*)&x[(size_t)r1 * XDIM + kbase + kc1];
  uint4 pb0 = *(const uint4*)&Wcomb[(size_t)wrow0 * XDIM + kbase + kc0];
  uint4 pb1 = *(const uint4*)&Wcomb[(size_t)wrow1 * XDIM + kbase + kc1];
  f32x4 acc[2][2] = {};
  const int NK = 12;  // 768 / 64
  for (int kt = 0; kt < NK; ++kt) {
    u16* as = As + (kt & 1) * (64 * LD64);
    u16* bs = Bs + (kt & 1) * (64 * LD64);
    *(uint4*)&as[r0 * LD64 + kc0] = pa0;
    *(uint4*)&as[r1 * LD64 + kc1] = pa1;
    *(uint4*)&bs[r0 * LD64 + kc0] = pb0;
    *(uint4*)&bs[r1 * LD64 + kc1] = pb1;
    __syncthreads();
    if (kt + 1 < NK) {
      int k0 = kbase + (kt + 1) * 64;
      pa0 = *(const uint4*)&x[(size_t)r0 * XDIM + k0 + kc0];
      pa1 = *(const uint4*)&x[(size_t)r1 * XDIM + k0 + kc1];
      pb0 = *(const uint4*)&Wcomb[(size_t)wrow0 * XDIM + k0 + kc0];
      pb1 = *(const uint4*)&Wcomb[(size_t)wrow1 * XDIM + k0 + kc1];
    }
    #pragma unroll
    for (int ks = 0; ks < 2; ++ks) {
      bf16x8 a0 = *(const bf16x8*)&as[(wm * 32 + fr) * LD64 + ks * 32 + kg];
      bf16x8 a1 = *(const bf16x8*)&as[(wm * 32 + 16 + fr) * LD64 + ks * 32 + kg];
      bf16x8 b0 = *(const bf16x8*)&bs[(wn * 32 + fr) * LD64 + ks * 32 + kg];
      bf16x8 b1 = *(const bf16x8*)&bs[(wn * 32 + 16 + fr) * LD64 + ks * 32 + kg];
      acc[0][0] = __builtin_amdgcn_mfma_f32_16x16x32_bf16(a0, b0, acc[0][0], 0, 0, 0);
      acc[0][1] = __builtin_amdgcn_mfma_f32_16x16x32_bf16(a0, b1, acc[0][1], 0, 0, 0);
      acc[1][0] = __builtin_amdgcn_mfma_f32_16x16x32_bf16(a1, b0, acc[1][0], 0, 0, 0);
      acc[1][1] = __builtin_amdgcn_mfma_f32_16x16x32_bf16(a1, b1, acc[1][1], 0, 0, 0);
    }
  }
  float* pout = pbuf + (size_t)(ksp * 32 + jt) * 4096;
  #pragma unroll
  for (int mi = 0; mi < 2; ++mi)
    for (int ni = 0; ni < 2; ++ni)
      #pragma unroll
      for (int r = 0; r < 4; ++r) {
        int m = wm * 32 + mi * 16 + rq * 4 + r;
        int n = wn * 32 + ni * 16 + fr;
        pout[m * 64 + n] = acc[mi][ni][r];
      }
}

// ---------------- S3b: reduce partials + biases + LSTM pointwise; h also -> hall[step] ----------------
__global__ __launch_bounds__(256) void k_lstm_fin(const float* __restrict__ pbuf,
    const float* __restrict__ bih, const float* __restrict__ bhh,
    float* __restrict__ c, u16* __restrict__ h, u16* __restrict__ hall, int step) {
  int jt = blockIdx.x, tid = threadIdx.x;
  #pragma unroll
  for (int ii = 0; ii < 4; ++ii) {
    int idx = tid + ii * 256;     // 0..1023
    int bb = idx >> 4, jj = idx & 15;
    int j = jt * 16 + jj;
    float g4[4];
    #pragma unroll
    for (int g = 0; g < 4; ++g) {
      float s = 0.f;
      #pragma unroll
      for (int ks = 0; ks < 4; ++ks)
        s += pbuf[(size_t)(ks * 32 + jt) * 4096 + bb * 64 + g * 16 + jj];
      g4[g] = s;
    }
    float iv = g4[0] + bih[j]        + bhh[j];
    float fv = g4[1] + bih[512 + j]  + bhh[512 + j];
    float gv = g4[2] + bih[1024 + j] + bhh[1024 + j];
    float ov = g4[3] + bih[1536 + j] + bhh[1536 + j];
    float co = c[bb * DEC + j];
    float cn = sigm(fv) * co + sigm(iv) * tanh_fast(gv);
    float hn = sigm(ov) * tanh_fast(cn);
    c[bb * DEC + j] = cn;
    u16 hb = f2bf(hn);
    h[bb * DEC + j] = hb;
    hall[(size_t)(step * BB + bb) * DEC + j] = hb;
  }
}

extern "C" void kernel_launch(void* const* d_in, const int* in_sizes, int n_in,
                              void* d_out, int out_size, void* d_ws, size_t ws_size,
                              hipStream_t stream) {
  const float* img   = (const float*)d_in[0];
  const int*   cap   = (const int*)  d_in[1];
  const float* Winh  = (const float*)d_in[2];
  const float* binh  = (const float*)d_in[3];
  const float* Winc  = (const float*)d_in[4];
  const float* binc  = (const float*)d_in[5];
  const float* Wdec  = (const float*)d_in[6];
  const float* bdec  = (const float*)d_in[7];
  const float* Wenc  = (const float*)d_in[8];
  const float* benc  = (const float*)d_in[9];
  const float* Wfin  = (const float*)d_in[10];
  const float* bfin  = (const float*)d_in[11];
  const float* Wgate = (const float*)d_in[12];
  const float* bgate = (const float*)d_in[13];
  const float* Wout  = (const float*)d_in[14];
  const float* bout  = (const float*)d_in[15];
  const float* emb   = (const float*)d_in[16];
  const float* Wih   = (const float*)d_in[17];
  const float* bih   = (const float*)d_in[18];
  const float* Whh   = (const float*)d_in[19];
  const float* bhh   = (const float*)d_in[20];

  // ---- workspace layout (round-8 proven; e_ws slot now unused) ----
  char* ws = (char*)d_ws;
  u16*   epj    = (u16*)  (ws);               // 12,845,056 B
  u16*   Winitb = (u16*)  (ws);               // prologue alias in epj
  u16*   avgb   = (u16*)  (ws + 4194304);     // prologue alias in epj
  u16*   Wcomb  = (u16*)  (ws + 12845056);    // 12,582,912 B
  u16*   Woutb2 = (u16*)  (ws + 25427968);    // 10,354,688 B (10112 x 512)
  u16*   Wgateb = (u16*)  (ws + 35782656);    //  2,097,152 B
  u16*   Wdecb  = (u16*)  (ws + 37879808);    //    524,288 B
  u16*   Wencb  = (u16*)  (ws + 38404096);    //  2,097,152 B
  float* pbuf   = (float*)(ws + 40501248);    //  2,097,152 B
  u16*   h      = (u16*)  (ws + 42598400);    //     65,536 B
  float* c      = (float*)(ws + 42663936);    //    131,072 B
  u16*   x      = (u16*)  (ws + 42846208);    //    393,216 B
  float* uh     = (float*)(ws + 43239424);    //    131,072 B
  float* gate   = (float*)(ws + 43370496);    //    524,288 B
  u16*   hall   = (u16*)  (ws + 43894784);    //  1,310,720 B (1280 x 512)
  u16*   imgb   = (u16*)  (ws + 45205504);    // 51,380,224 B -> total 96,585,728
  const bool use_imgb = (ws_size >= 96585728ull);

  float* preds  = (float*)d_out;                                  // (64,19,10000)
  float* alphas = (float*)d_out + (size_t)BB * TT * VOCAB;        // (64,19,196)

  // prologue: f32->bf16 conversions
  k_cvt_simple<<<512,  256, 0, stream>>>(Winitb,             Winh, 262144);
  k_cvt_simple<<<512,  256, 0, stream>>>(Winitb + 512 * ENC, Winc, 262144);
  if (use_imgb) {
    k_cvt_simple<<<4096, 256, 0, stream>>>(imgb,  img,  6422528);
    k_cvt_simple<<<512,  256, 0, stream>>>(Wencb, Wenc, 262144);
  }
  k_cvt_simple<<<512,  256, 0, stream>>>(Wgateb, Wgate, 262144);
  k_cvt_simple<<<128,  256, 0, stream>>>(Wdecb,  Wdec,  65536);
  k_cvt_pad   <<<2048, 256, 0, stream>>>(Woutb2, Wout);
  k_cvt_comb  <<<2048, 256, 0, stream>>>(Wcomb,  Wih, Whh);

  if (use_imgb)
    k_avg<0><<<dim3(BB, 8), 256, 0, stream>>>(imgb, img, avgb);
  else
    k_avg<1><<<dim3(BB, 8), 256, 0, stream>>>(imgb, img, avgb);
  k_init_mfma<<<16, 256, 0, stream>>>(avgb, Winitb, binh, binc, h, c);
  if (use_imgb)
    k_encproj<0><<<416, 256, 0, stream>>>(imgb, img, Wencb, Wenc, benc, epj);
  else
    k_encproj<1><<<416, 256, 0, stream>>>(imgb, img, Wencb, Wenc, benc, epj);
  // U_h + gate for step 0 (+ h0 -> x staging)
  k_hcons<<<40, 256, 0, stream>>>(h, Wdecb, bdec, Wgateb, bgate, uh, gate, x);
  for (int t = 0; t < TT; ++t) {
    if (use_imgb)
      k_attctx<0><<<dim3(BB, 4), 256, 0, stream>>>(uh, epj, Wfin, bfin, cap, emb,
                                                   gate, imgb, img, x, alphas, t);
    else
      k_attctx<1><<<dim3(BB, 4), 256, 0, stream>>>(uh, epj, Wfin, bfin, cap, emb,
                                                   gate, imgb, img, x, alphas, t);
    k_lstm_part<<<dim3(32, 4), 256, 0, stream>>>(x, Wcomb, pbuf);
    k_lstm_fin<<<32, 256, 0, stream>>>(pbuf, bih, bhh, c, h, hall, t);
    if (t + 1 < TT)
      k_hcons<<<40, 256, 0, stream>>>(h, Wdecb, bdec, Wgateb, bgate, uh, gate, x);
  }
  k_logits<<<dim3(10, 79), 256, 0, stream>>>(hall, Woutb2, bout, preds);
}

// Round 17
// 1176.974 us; speedup vs baseline: 1.3750x; 1.3750x over previous
//
#include <hip/hip_runtime.h>
#include <hip/hip_bf16.h>

typedef unsigned short u16;
typedef unsigned int   u32;

#define BB    64
#define PP    196
#define ENC   2048
#define DEC   512
#define ATT   512
#define EMB   512
#define VOCAB 10000
#define VPAD2 10112   // W_out padded rows (79 * 128)
#define TT    19
#define LCAP  20
#define XDIM  3072    // [e_t(512) | gated_ctx(2048) | h(512)]
#define LDSTR 40      // LDS row stride (32 + 8 pad) for BK=32 kernels
#define LD64  72      // LDS row stride (64 + 8 pad) for BK=64 ping-pong kernels

typedef __bf16 bf16x8 __attribute__((ext_vector_type(8)));
typedef float  f32x4  __attribute__((ext_vector_type(4)));

__device__ __forceinline__ float bf2f(u16 u) {
  union { float f; u32 i; } v; v.i = ((u32)u) << 16; return v.f;
}
__device__ __forceinline__ u16 f2bf(float f) {
  u32 x = __float_as_uint(f);
  u32 r = (x + 0x7FFFu + ((x >> 16) & 1u)) >> 16;
  return (u16)r;
}
__device__ __forceinline__ u32 pack2(float a, float b) {
  return (u32)f2bf(a) | ((u32)f2bf(b) << 16);
}
__device__ __forceinline__ float wred_sum(float v) {
  #pragma unroll
  for (int off = 32; off > 0; off >>= 1) v += __shfl_xor(v, off, 64);
  return v;
}
__device__ __forceinline__ float wred_max(float v) {
  #pragma unroll
  for (int off = 32; off > 0; off >>= 1) v = fmaxf(v, __shfl_xor(v, off, 64));
  return v;
}
__device__ __forceinline__ float tanh_fast(float x) {
  return 1.f - 2.f / (__expf(2.f * x) + 1.f);
}
__device__ __forceinline__ float sigm(float x) {
  return 1.f / (1.f + __expf(-x));
}

// ---------------- CVT: f32 -> bf16 ----------------
__global__ __launch_bounds__(256) void k_cvt_simple(u16* __restrict__ dst,
    const float* __restrict__ src, int n4) {
  int stride = gridDim.x * blockDim.x;
  for (int i = blockIdx.x * blockDim.x + threadIdx.x; i < n4; i += stride) {
    float4 v = ((const float4*)src)[i];
    ((uint2*)dst)[i] = make_uint2(pack2(v.x, v.y), pack2(v.z, v.w));
  }
}

// W_out (10000x512) -> bf16 padded to 10112 rows (pad rows = 0)
__global__ __launch_bounds__(256) void k_cvt_pad(u16* __restrict__ dst,
    const float* __restrict__ src) {
  int total = VPAD2 * (DEC / 2);
  int stride = gridDim.x * blockDim.x;
  for (int i = blockIdx.x * blockDim.x + threadIdx.x; i < total; i += stride) {
    int row = i >> 8, c2 = i & 255;
    u32 v = 0;
    if (row < VOCAB) {
      float2 f = ((const float2*)src)[(size_t)row * 256 + c2];
      v = pack2(f.x, f.y);
    }
    ((u32*)dst)[i] = v;
  }
}

// Wcomb[2048][3072] = [W_ih (2048x2560) | W_hh (2048x512)] -> bf16
__global__ __launch_bounds__(256) void k_cvt_comb(u16* __restrict__ dst,
    const float* __restrict__ Wih, const float* __restrict__ Whh) {
  int j = blockIdx.x;
  for (int t = threadIdx.x; t < 768; t += 256) {
    int col = t * 4;
    float4 v = (col < 2560)
        ? ((const float4*)(Wih + (size_t)j * 2560))[t]
        : ((const float4*)(Whh + (size_t)j * 512))[(col - 2560) >> 2];
    ((uint2*)(dst + (size_t)j * XDIM))[t] = make_uint2(pack2(v.x, v.y), pack2(v.z, v.w));
  }
}

// ---------------- P0a: avgb = mean_p img -> bf16 (reads imgb when available) ----------------
template <int SRC>
__global__ __launch_bounds__(256) void k_avg(const u16* __restrict__ imgb,
    const float* __restrict__ imgf, u16* __restrict__ avgb) {
  int b = blockIdx.x;
  int col = blockIdx.y * 256 + threadIdx.x;
  float s = 0.f;
  if (SRC == 0) {
    const u16* base = imgb + (size_t)b * PP * ENC + col;
    for (int p = 0; p < PP; ++p) s += bf2f(base[(size_t)p * ENC]);
  } else {
    const float* base = imgf + (size_t)b * PP * ENC + col;
    for (int p = 0; p < PP; ++p) s += base[(size_t)p * ENC];
  }
  avgb[b * ENC + col] = f2bf(s * (1.f / PP));
}

// ---------------- P0b: [h0|c0] = tanh(avg @ [Wh;Wc]^T + b)  (MFMA, N=1024, K=2048) ----------------
__global__ __launch_bounds__(256) void k_init_mfma(const u16* __restrict__ avgb,
    const u16* __restrict__ Winitb, const float* __restrict__ bh,
    const float* __restrict__ bc, u16* __restrict__ h, float* __restrict__ c) {
  __shared__ __align__(16) u16 As[2 * 64 * LD64];
  __shared__ __align__(16) u16 Bs[2 * 64 * LD64];
  int n0 = blockIdx.x * 64;
  int tid = threadIdx.x, wv = tid >> 6, lane = tid & 63;
  int wm = wv >> 1, wn = wv & 1;
  int fr = lane & 15, kg = (lane >> 4) * 8, rq = lane >> 4;
  int r0 = tid >> 3, kc0 = (tid & 7) * 8;
  int r1 = (tid + 256) >> 3, kc1 = ((tid + 256) & 7) * 8;
  uint4 pa0 = *(const uint4*)&avgb[(size_t)r0 * ENC + kc0];
  uint4 pa1 = *(const uint4*)&avgb[(size_t)r1 * ENC + kc1];
  uint4 pb0 = *(const uint4*)&Winitb[(size_t)(n0 + r0) * ENC + kc0];
  uint4 pb1 = *(const uint4*)&Winitb[(size_t)(n0 + r1) * ENC + kc1];
  f32x4 acc[2][2] = {};
  const int NK = ENC / 64;  // 32
  for (int kt = 0; kt < NK; ++kt) {
    u16* as = As + (kt & 1) * (64 * LD64);
    u16* bs = Bs + (kt & 1) * (64 * LD64);
    *(uint4*)&as[r0 * LD64 + kc0] = pa0;
    *(uint4*)&as[r1 * LD64 + kc1] = pa1;
    *(uint4*)&bs[r0 * LD64 + kc0] = pb0;
    *(uint4*)&bs[r1 * LD64 + kc1] = pb1;
    __syncthreads();
    if (kt + 1 < NK) {
      int k0 = (kt + 1) * 64;
      pa0 = *(const uint4*)&avgb[(size_t)r0 * ENC + k0 + kc0];
      pa1 = *(const uint4*)&avgb[(size_t)r1 * ENC + k0 + kc1];
      pb0 = *(const uint4*)&Winitb[(size_t)(n0 + r0) * ENC + k0 + kc0];
      pb1 = *(const uint4*)&Winitb[(size_t)(n0 + r1) * ENC + k0 + kc1];
    }
    #pragma unroll
    for (int ks = 0; ks < 2; ++ks) {
      bf16x8 a0 = *(const bf16x8*)&as[(wm * 32 + fr) * LD64 + ks * 32 + kg];
      bf16x8 a1 = *(const bf16x8*)&as[(wm * 32 + 16 + fr) * LD64 + ks * 32 + kg];
      bf16x8 b0 = *(const bf16x8*)&bs[(wn * 32 + fr) * LD64 + ks * 32 + kg];
      bf16x8 b1 = *(const bf16x8*)&bs[(wn * 32 + 16 + fr) * LD64 + ks * 32 + kg];
      acc[0][0] = __builtin_amdgcn_mfma_f32_16x16x32_bf16(a0, b0, acc[0][0], 0, 0, 0);
      acc[0][1] = __builtin_amdgcn_mfma_f32_16x16x32_bf16(a0, b1, acc[0][1], 0, 0, 0);
      acc[1][0] = __builtin_amdgcn_mfma_f32_16x16x32_bf16(a1, b0, acc[1][0], 0, 0, 0);
      acc[1][1] = __builtin_amdgcn_mfma_f32_16x16x32_bf16(a1, b1, acc[1][1], 0, 0, 0);
    }
  }
  #pragma unroll
  for (int mi = 0; mi < 2; ++mi)
    for (int ni = 0; ni < 2; ++ni)
      #pragma unroll
      for (int r = 0; r < 4; ++r) {
        int m = wm * 32 + mi * 16 + rq * 4 + r;
        int n = n0 + wn * 32 + ni * 16 + fr;
        float v = acc[mi][ni][r];
        if (n < DEC) h[m * DEC + n] = f2bf(tanh_fast(v + bh[n]));
        else         c[m * DEC + (n - DEC)] = tanh_fast(v + bc[n - DEC]);
      }
}

// ---------------- P1: enc_proj = img @ W_enc^T + b_enc (128x128 tiles, BK=32) ----------------
// XCD swizzle: mt=(bid&7)+8*(bid>>5), nt=(bid>>3)&3 -> the 4 n-blocks of one m-tile share
// bid%8 (same XCD) so the A-tile is fetched into one L2 only. Grid 416, mt>=98 returns.
template <int SRC>
__global__ __launch_bounds__(256) void k_encproj(
    const u16* __restrict__ Ab, const float* __restrict__ Af,
    const u16* __restrict__ Wb, const float* __restrict__ Wf,
    const float* __restrict__ benc, u16* __restrict__ epj) {
  __shared__ __align__(16) u16 As[128 * LDSTR];
  __shared__ __align__(16) u16 Bs[128 * LDSTR];
  int bid = blockIdx.x;
  int mt = (bid & 7) + 8 * (bid >> 5);
  int nt = (bid >> 3) & 3;
  if (mt >= 98) return;
  int m0 = mt * 128, n0 = nt * 128;
  int tid = threadIdx.x, wv = tid >> 6, lane = tid & 63;
  int wm = wv >> 1, wn = wv & 1;
  int fr = lane & 15, kg = (lane >> 4) * 8, rq = lane >> 4;
  f32x4 acc[4][4] = {};
  for (int k0 = 0; k0 < ENC; k0 += 32) {
    __syncthreads();
    #pragma unroll
    for (int i = 0; i < 2; ++i) {
      int id = tid + i * 256;
      int r = id >> 2, kc = id & 3;
      if (SRC == 0) {
        *(uint4*)(&As[r * LDSTR + kc * 8]) = *(const uint4*)(&Ab[(size_t)(m0 + r) * ENC + k0 + kc * 8]);
        *(uint4*)(&Bs[r * LDSTR + kc * 8]) = *(const uint4*)(&Wb[(size_t)(n0 + r) * ENC + k0 + kc * 8]);
      } else {
        const float* asrc = &Af[(size_t)(m0 + r) * ENC + k0 + kc * 8];
        float4 f0 = ((const float4*)asrc)[0];
        float4 f1 = ((const float4*)asrc)[1];
        *(uint4*)(&As[r * LDSTR + kc * 8]) =
            make_uint4(pack2(f0.x, f0.y), pack2(f0.z, f0.w),
                       pack2(f1.x, f1.y), pack2(f1.z, f1.w));
        const float* bsrc = &Wf[(size_t)(n0 + r) * ENC + k0 + kc * 8];
        float4 g0 = ((const float4*)bsrc)[0];
        float4 g1 = ((const float4*)bsrc)[1];
        *(uint4*)(&Bs[r * LDSTR + kc * 8]) =
            make_uint4(pack2(g0.x, g0.y), pack2(g0.z, g0.w),
                       pack2(g1.x, g1.y), pack2(g1.z, g1.w));
      }
    }
    __syncthreads();
    bf16x8 af[4], bfr[4];
    #pragma unroll
    for (int i = 0; i < 4; ++i) {
      af[i]  = *(const bf16x8*)(&As[(wm * 64 + i * 16 + fr) * LDSTR + kg]);
      bfr[i] = *(const bf16x8*)(&Bs[(wn * 64 + i * 16 + fr) * LDSTR + kg]);
    }
    #pragma unroll
    for (int mi = 0; mi < 4; ++mi)
      #pragma unroll
      for (int ni = 0; ni < 4; ++ni)
        acc[mi][ni] = __builtin_amdgcn_mfma_f32_16x16x32_bf16(af[mi], bfr[ni], acc[mi][ni], 0, 0, 0);
  }
  #pragma unroll
  for (int mi = 0; mi < 4; ++mi)
    for (int ni = 0; ni < 4; ++ni)
      #pragma unroll
      for (int r = 0; r < 4; ++r) {
        int m = m0 + wm * 64 + mi * 16 + rq * 4 + r;
        int n = n0 + wn * 64 + ni * 16 + fr;
        epj[(size_t)m * ATT + n] = f2bf(acc[mi][ni][r] + benc[n]);
      }
}

// ---------------- LOGITS (end of loop, batched over all 19 steps) ----------------
__global__ __launch_bounds__(256) void k_logits(const u16* __restrict__ hall,
    const u16* __restrict__ Woutb2, const float* __restrict__ bout,
    float* __restrict__ preds) {
  __shared__ __align__(16) u16 As[128 * LDSTR];
  __shared__ __align__(16) u16 Bs[128 * LDSTR];
  int m0 = blockIdx.x * 128, n0 = blockIdx.y * 128;
  int tid = threadIdx.x, wv = tid >> 6, lane = tid & 63;
  int wm = wv >> 1, wn = wv & 1;
  int fr = lane & 15, kg = (lane >> 4) * 8, rq = lane >> 4;
  f32x4 acc[4][4] = {};
  for (int k0 = 0; k0 < DEC; k0 += 32) {
    __syncthreads();
    #pragma unroll
    for (int i = 0; i < 2; ++i) {
      int id = tid + i * 256;
      int r = id >> 2, kc = id & 3;
      *(uint4*)(&As[r * LDSTR + kc * 8]) = *(const uint4*)(&hall[(size_t)(m0 + r) * DEC + k0 + kc * 8]);
      *(uint4*)(&Bs[r * LDSTR + kc * 8]) = *(const uint4*)(&Woutb2[(size_t)(n0 + r) * DEC + k0 + kc * 8]);
    }
    __syncthreads();
    bf16x8 af[4], bfr[4];
    #pragma unroll
    for (int i = 0; i < 4; ++i) {
      af[i]  = *(const bf16x8*)(&As[(wm * 64 + i * 16 + fr) * LDSTR + kg]);
      bfr[i] = *(const bf16x8*)(&Bs[(wn * 64 + i * 16 + fr) * LDSTR + kg]);
    }
    #pragma unroll
    for (int mi = 0; mi < 4; ++mi)
      #pragma unroll
      for (int ni = 0; ni < 4; ++ni)
        acc[mi][ni] = __builtin_amdgcn_mfma_f32_16x16x32_bf16(af[mi], bfr[ni], acc[mi][ni], 0, 0, 0);
  }
  #pragma unroll
  for (int mi = 0; mi < 4; ++mi)
    for (int ni = 0; ni < 4; ++ni)
      #pragma unroll
      for (int r = 0; r < 4; ++r) {
        int m = m0 + wm * 64 + mi * 16 + rq * 4 + r;
        int n = n0 + wn * 64 + ni * 16 + fr;
        if (m < TT * BB && n < VOCAB) {
          int t = m >> 6, b = m & 63;
          preds[(size_t)b * (TT * VOCAB) + (size_t)t * VOCAB + n] = acc[mi][ni][r] + bout[n];
        }
      }
}

// ---------------- HC (critical only): U_h (8 blk) + attn-gate (32 blk); BK=64 ping-pong ----------------
__global__ __launch_bounds__(256) void k_hcons(const u16* __restrict__ h,
    const u16* __restrict__ Wdecb, const float* __restrict__ bdec,
    const u16* __restrict__ Wgateb, const float* __restrict__ bgate,
    float* __restrict__ uh, float* __restrict__ gate, u16* __restrict__ x) {
  __shared__ __align__(16) u16 As[2 * 64 * LD64];
  __shared__ __align__(16) u16 Bs[2 * 64 * LD64];
  int bid = blockIdx.x;
  int tid = threadIdx.x, wv = tid >> 6, lane = tid & 63;
  int wm = wv >> 1, wn = wv & 1;
  int fr = lane & 15, kg = (lane >> 4) * 8, rq = lane >> 4;

  if (bid == 0) {  // stage h into x[:,2560:3072] for this step's LSTM GEMM
    for (int i = tid; i < 16384; i += 256) {
      int b = i >> 8, jp = (i & 255) * 2;
      *(u32*)(&x[(size_t)b * XDIM + 2560 + jp]) = *(const u32*)(&h[b * DEC + jp]);
    }
  }

  int role, nt; const u16* Wsrc;
  if (bid < 8) { role = 0; nt = bid;     Wsrc = Wdecb;  }
  else         { role = 1; nt = bid - 8; Wsrc = Wgateb; }
  int n0 = nt * 64;

  int r0 = tid >> 3, kc0 = (tid & 7) * 8;
  int r1 = (tid + 256) >> 3, kc1 = ((tid + 256) & 7) * 8;
  uint4 pa0 = *(const uint4*)&h[(size_t)r0 * DEC + kc0];
  uint4 pa1 = *(const uint4*)&h[(size_t)r1 * DEC + kc1];
  uint4 pb0 = *(const uint4*)&Wsrc[(size_t)(n0 + r0) * DEC + kc0];
  uint4 pb1 = *(const uint4*)&Wsrc[(size_t)(n0 + r1) * DEC + kc1];
  f32x4 acc[2][2] = {};
  const int NK = DEC / 64;  // 8
  for (int kt = 0; kt < NK; ++kt) {
    u16* as = As + (kt & 1) * (64 * LD64);
    u16* bs = Bs + (kt & 1) * (64 * LD64);
    *(uint4*)&as[r0 * LD64 + kc0] = pa0;
    *(uint4*)&as[r1 * LD64 + kc1] = pa1;
    *(uint4*)&bs[r0 * LD64 + kc0] = pb0;
    *(uint4*)&bs[r1 * LD64 + kc1] = pb1;
    __syncthreads();
    if (kt + 1 < NK) {
      int k0 = (kt + 1) * 64;
      pa0 = *(const uint4*)&h[(size_t)r0 * DEC + k0 + kc0];
      pa1 = *(const uint4*)&h[(size_t)r1 * DEC + k0 + kc1];
      pb0 = *(const uint4*)&Wsrc[(size_t)(n0 + r0) * DEC + k0 + kc0];
      pb1 = *(const uint4*)&Wsrc[(size_t)(n0 + r1) * DEC + k0 + kc1];
    }
    #pragma unroll
    for (int ks = 0; ks < 2; ++ks) {
      bf16x8 a0 = *(const bf16x8*)&as[(wm * 32 + fr) * LD64 + ks * 32 + kg];
      bf16x8 a1 = *(const bf16x8*)&as[(wm * 32 + 16 + fr) * LD64 + ks * 32 + kg];
      bf16x8 b0 = *(const bf16x8*)&bs[(wn * 32 + fr) * LD64 + ks * 32 + kg];
      bf16x8 b1 = *(const bf16x8*)&bs[(wn * 32 + 16 + fr) * LD64 + ks * 32 + kg];
      acc[0][0] = __builtin_amdgcn_mfma_f32_16x16x32_bf16(a0, b0, acc[0][0], 0, 0, 0);
      acc[0][1] = __builtin_amdgcn_mfma_f32_16x16x32_bf16(a0, b1, acc[0][1], 0, 0, 0);
      acc[1][0] = __builtin_amdgcn_mfma_f32_16x16x32_bf16(a1, b0, acc[1][0], 0, 0, 0);
      acc[1][1] = __builtin_amdgcn_mfma_f32_16x16x32_bf16(a1, b1, acc[1][1], 0, 0, 0);
    }
  }
  #pragma unroll
  for (int mi = 0; mi < 2; ++mi)
    for (int ni = 0; ni < 2; ++ni)
      #pragma unroll
      for (int r = 0; r < 4; ++r) {
        int m = wm * 32 + mi * 16 + rq * 4 + r;
        int n = n0 + wn * 32 + ni * 16 + fr;
        float v = acc[mi][ni][r];
        if (role == 0) uh[m * DEC + n] = v + bdec[n];
        else           gate[m * ENC + n] = sigm(v + bgate[n]);
      }
}

// ---------------- S1: e scores (+ copy e_t into x) ----------------
__global__ __launch_bounds__(256) void k_escore(const float* __restrict__ uh,
    const u16* __restrict__ epj, const float* __restrict__ wfin, const float* __restrict__ bfin,
    const int* __restrict__ captions, const float* __restrict__ emb,
    float* __restrict__ e_ws, u16* __restrict__ x, int step) {
  __shared__ float s_uh[ATT], s_wf[ATT];
  int b = blockIdx.x, pt = blockIdx.y;
  int tid = threadIdx.x;
  for (int i = tid; i < ATT; i += 256) { s_uh[i] = uh[b * ATT + i]; s_wf[i] = wfin[i]; }
  __syncthreads();
  if (pt == 0) {
    int capv = captions[b * LCAP + step];
    float2 f = ((const float2*)(emb + (size_t)capv * EMB))[tid];
    ((u32*)(x + (size_t)b * XDIM))[tid] = pack2(f.x, f.y);
  }
  int w = tid >> 6, lane = tid & 63;
  float b0 = bfin[0];
  for (int pl = w; pl < 49; pl += 4) {
    int p = pt * 49 + pl;
    const u16* row = epj + (size_t)(b * PP + p) * ATT;
    float acc = 0.f;
    #pragma unroll
    for (int ki = 0; ki < 8; ++ki) {
      int a = lane + ki * 64;
      acc += tanh_fast(bf2f(row[a]) + s_uh[a]) * s_wf[a];
    }
    acc = wred_sum(acc);
    if (lane == 0) e_ws[b * PP + p] = acc + b0;
  }
}

// ---------------- S2: softmax + context + gated ctx into x ----------------
template <int SRC>
__global__ __launch_bounds__(256) void k_ctx(const float* __restrict__ e_ws,
    const float* __restrict__ gate, const u16* __restrict__ imgb,
    const float* __restrict__ imgf,
    u16* __restrict__ x, float* __restrict__ alphas, int step) {
  __shared__ float s_a[PP];
  int b = blockIdx.x, et = blockIdx.y;
  int tid = threadIdx.x;
  if (tid < PP) s_a[tid] = e_ws[b * PP + tid];
  __syncthreads();
  if (tid < 64) {
    float v0 = s_a[tid], v1 = s_a[tid + 64], v2 = s_a[tid + 128];
    float v3 = (tid + 192 < PP) ? s_a[tid + 192] : -1e30f;
    float m = wred_max(fmaxf(fmaxf(v0, v1), fmaxf(v2, v3)));
    float e0 = __expf(v0 - m), e1 = __expf(v1 - m), e2 = __expf(v2 - m);
    float e3 = (tid + 192 < PP) ? __expf(v3 - m) : 0.f;
    float inv = 1.f / wred_sum(e0 + e1 + e2 + e3);
    s_a[tid] = e0 * inv; s_a[tid + 64] = e1 * inv; s_a[tid + 128] = e2 * inv;
    if (tid + 192 < PP) s_a[tid + 192] = e3 * inv;
  }
  __syncthreads();
  if (et == 0 && tid < PP)
    alphas[(size_t)b * (TT * PP) + (size_t)step * PP + tid] = s_a[tid];
  int e0i = et * 512 + tid * 2;
  float c0 = 0.f, c1 = 0.f;
  if (SRC == 0) {
    const u16* ib = imgb + (size_t)b * PP * ENC + e0i;
    for (int p = 0; p < PP; ++p) {
      u32 v = *(const u32*)(ib + (size_t)p * ENC);
      float ap = s_a[p];
      c0 += ap * bf2f((u16)(v & 0xFFFF));
      c1 += ap * bf2f((u16)(v >> 16));
    }
  } else {
    const float* ib = imgf + (size_t)b * PP * ENC + e0i;
    for (int p = 0; p < PP; ++p) {
      float2 v = *(const float2*)(ib + (size_t)p * ENC);
      float ap = s_a[p];
      c0 += ap * v.x;
      c1 += ap * v.y;
    }
  }
  float g0 = gate[b * ENC + e0i], g1 = gate[b * ENC + e0i + 1];
  *(u32*)(&x[(size_t)b * XDIM + 512 + e0i]) = pack2(c0 * g0, c1 * g1);
}

// ---------------- S3a: gates GEMM partials, K split 4 ways (BK=64 ping-pong) ----------------
__global__ __launch_bounds__(256) void k_lstm_part(const u16* __restrict__ x,
    const u16* __restrict__ Wcomb, float* __restrict__ pbuf) {
  __shared__ __align__(16) u16 As[2 * 64 * LD64];
  __shared__ __align__(16) u16 Bs[2 * 64 * LD64];
  int jt = blockIdx.x, ksp = blockIdx.y;
  int kbase = ksp * 768;
  int tid = threadIdx.x, wv = tid >> 6, lane = tid & 63;
  int wm = wv >> 1, wn = wv & 1;
  int fr = lane & 15, kg = (lane >> 4) * 8, rq = lane >> 4;
  int r0 = tid >> 3, kc0 = (tid & 7) * 8;
  int r1 = (tid + 256) >> 3, kc1 = ((tid + 256) & 7) * 8;
  int wrow0 = (r0 >> 4) * 512 + jt * 16 + (r0 & 15);
  int wrow1 = (r1 >> 4) * 512 + jt * 16 + (r1 & 15);
  uint4 pa0 = *(const uint4*)&x[(size_t)r0 * XDIM + kbase + kc0];
  uint4 pa1 = *(const uint4*)&x[(size_t)r1 * XDIM + kbase + kc1];
  uint4 pb0 = *(const uint4*)&Wcomb[(size_t)wrow0 * XDIM + kbase + kc0];
  uint4 pb1 = *(const uint4*)&Wcomb[(size_t)wrow1 * XDIM + kbase + kc1];
  f32x4 acc[2][2] = {};
  const int NK = 12;  // 768 / 64
  for (int kt = 0; kt < NK; ++kt) {
    u16* as = As + (kt & 1) * (64 * LD64);
    u16* bs = Bs + (kt & 1) * (64 * LD64);
    *(uint4*)&as[r0 * LD64 + kc0] = pa0;
    *(uint4*)&as[r1 * LD64 + kc1] = pa1;
    *(uint4*)&bs[r0 * LD64 + kc0] = pb0;
    *(uint4*)&bs[r1 * LD64 + kc1] = pb1;
    __syncthreads();
    if (kt + 1 < NK) {
      int k0 = kbase + (kt + 1) * 64;
      pa0 = *(const uint4*)&x[(size_t)r0 * XDIM + k0 + kc0];
      pa1 = *(const uint4*)&x[(size_t)r1 * XDIM + k0 + kc1];
      pb0 = *(const uint4*)&Wcomb[(size_t)wrow0 * XDIM + k0 + kc0];
      pb1 = *(const uint4*)&Wcomb[(size_t)wrow1 * XDIM + k0 + kc1];
    }
    #pragma unroll
    for (int ks = 0; ks < 2; ++ks) {
      bf16x8 a0 = *(const bf16x8*)&as[(wm * 32 + fr) * LD64 + ks * 32 + kg];
      bf16x8 a1 = *(const bf16x8*)&as[(wm * 32 + 16 + fr) * LD64 + ks * 32 + kg];
      bf16x8 b0 = *(const bf16x8*)&bs[(wn * 32 + fr) * LD64 + ks * 32 + kg];
      bf16x8 b1 = *(const bf16x8*)&bs[(wn * 32 + 16 + fr) * LD64 + ks * 32 + kg];
      acc[0][0] = __builtin_amdgcn_mfma_f32_16x16x32_bf16(a0, b0, acc[0][0], 0, 0, 0);
      acc[0][1] = __builtin_amdgcn_mfma_f32_16x16x32_bf16(a0, b1, acc[0][1], 0, 0, 0);
      acc[1][0] = __builtin_amdgcn_mfma_f32_16x16x32_bf16(a1, b0, acc[1][0], 0, 0, 0);
      acc[1][1] = __builtin_amdgcn_mfma_f32_16x16x32_bf16(a1, b1, acc[1][1], 0, 0, 0);
    }
  }
  float* pout = pbuf + (size_t)(ksp * 32 + jt) * 4096;
  #pragma unroll
  for (int mi = 0; mi < 2; ++mi)
    for (int ni = 0; ni < 2; ++ni)
      #pragma unroll
      for (int r = 0; r < 4; ++r) {
        int m = wm * 32 + mi * 16 + rq * 4 + r;
        int n = wn * 32 + ni * 16 + fr;
        pout[m * 64 + n] = acc[mi][ni][r];
      }
}

// ---------------- S3b: reduce partials + biases + LSTM pointwise; h also -> hall[step] ----------------
__global__ __launch_bounds__(256) void k_lstm_fin(const float* __restrict__ pbuf,
    const float* __restrict__ bih, const float* __restrict__ bhh,
    float* __restrict__ c, u16* __restrict__ h, u16* __restrict__ hall, int step) {
  int jt = blockIdx.x, tid = threadIdx.x;
  #pragma unroll
  for (int ii = 0; ii < 4; ++ii) {
    int idx = tid + ii * 256;     // 0..1023
    int bb = idx >> 4, jj = idx & 15;
    int j = jt * 16 + jj;
    float g4[4];
    #pragma unroll
    for (int g = 0; g < 4; ++g) {
      float s = 0.f;
      #pragma unroll
      for (int ks = 0; ks < 4; ++ks)
        s += pbuf[(size_t)(ks * 32 + jt) * 4096 + bb * 64 + g * 16 + jj];
      g4[g] = s;
    }
    float iv = g4[0] + bih[j]        + bhh[j];
    float fv = g4[1] + bih[512 + j]  + bhh[512 + j];
    float gv = g4[2] + bih[1024 + j] + bhh[1024 + j];
    float ov = g4[3] + bih[1536 + j] + bhh[1536 + j];
    float co = c[bb * DEC + j];
    float cn = sigm(fv) * co + sigm(iv) * tanh_fast(gv);
    float hn = sigm(ov) * tanh_fast(cn);
    c[bb * DEC + j] = cn;
    u16 hb = f2bf(hn);
    h[bb * DEC + j] = hb;
    hall[(size_t)(step * BB + bb) * DEC + j] = hb;
  }
}

extern "C" void kernel_launch(void* const* d_in, const int* in_sizes, int n_in,
                              void* d_out, int out_size, void* d_ws, size_t ws_size,
                              hipStream_t stream) {
  const float* img   = (const float*)d_in[0];
  const int*   cap   = (const int*)  d_in[1];
  const float* Winh  = (const float*)d_in[2];
  const float* binh  = (const float*)d_in[3];
  const float* Winc  = (const float*)d_in[4];
  const float* binc  = (const float*)d_in[5];
  const float* Wdec  = (const float*)d_in[6];
  const float* bdec  = (const float*)d_in[7];
  const float* Wenc  = (const float*)d_in[8];
  const float* benc  = (const float*)d_in[9];
  const float* Wfin  = (const float*)d_in[10];
  const float* bfin  = (const float*)d_in[11];
  const float* Wgate = (const float*)d_in[12];
  const float* bgate = (const float*)d_in[13];
  const float* Wout  = (const float*)d_in[14];
  const float* bout  = (const float*)d_in[15];
  const float* emb   = (const float*)d_in[16];
  const float* Wih   = (const float*)d_in[17];
  const float* bih   = (const float*)d_in[18];
  const float* Whh   = (const float*)d_in[19];
  const float* bhh   = (const float*)d_in[20];

  // ---- workspace layout (round-8 proven) ----
  char* ws = (char*)d_ws;
  u16*   epj    = (u16*)  (ws);               // 12,845,056 B
  u16*   Winitb = (u16*)  (ws);               // prologue alias in epj
  u16*   avgb   = (u16*)  (ws + 4194304);     // prologue alias in epj
  u16*   Wcomb  = (u16*)  (ws + 12845056);    // 12,582,912 B
  u16*   Woutb2 = (u16*)  (ws + 25427968);    // 10,354,688 B (10112 x 512)
  u16*   Wgateb = (u16*)  (ws + 35782656);    //  2,097,152 B
  u16*   Wdecb  = (u16*)  (ws + 37879808);    //    524,288 B
  u16*   Wencb  = (u16*)  (ws + 38404096);    //  2,097,152 B
  float* pbuf   = (float*)(ws + 40501248);    //  2,097,152 B
  u16*   h      = (u16*)  (ws + 42598400);    //     65,536 B
  float* c      = (float*)(ws + 42663936);    //    131,072 B
  float* e_ws   = (float*)(ws + 42795008);    //     51,200 B
  u16*   x      = (u16*)  (ws + 42846208);    //    393,216 B
  float* uh     = (float*)(ws + 43239424);    //    131,072 B
  float* gate   = (float*)(ws + 43370496);    //    524,288 B
  u16*   hall   = (u16*)  (ws + 43894784);    //  1,310,720 B (1280 x 512)
  u16*   imgb   = (u16*)  (ws + 45205504);    // 51,380,224 B -> total 96,585,728
  const bool use_imgb = (ws_size >= 96585728ull);

  float* preds  = (float*)d_out;                                  // (64,19,10000)
  float* alphas = (float*)d_out + (size_t)BB * TT * VOCAB;        // (64,19,196)

  // prologue: f32->bf16 conversions
  k_cvt_simple<<<512,  256, 0, stream>>>(Winitb,             Winh, 262144);
  k_cvt_simple<<<512,  256, 0, stream>>>(Winitb + 512 * ENC, Winc, 262144);
  if (use_imgb) {
    k_cvt_simple<<<4096, 256, 0, stream>>>(imgb,  img,  6422528);
    k_cvt_simple<<<512,  256, 0, stream>>>(Wencb, Wenc, 262144);
  }
  k_cvt_simple<<<512,  256, 0, stream>>>(Wgateb, Wgate, 262144);
  k_cvt_simple<<<128,  256, 0, stream>>>(Wdecb,  Wdec,  65536);
  k_cvt_pad   <<<2048, 256, 0, stream>>>(Woutb2, Wout);
  k_cvt_comb  <<<2048, 256, 0, stream>>>(Wcomb,  Wih, Whh);

  if (use_imgb)
    k_avg<0><<<dim3(BB, 8), 256, 0, stream>>>(imgb, img, avgb);
  else
    k_avg<1><<<dim3(BB, 8), 256, 0, stream>>>(imgb, img, avgb);
  k_init_mfma<<<16, 256, 0, stream>>>(avgb, Winitb, binh, binc, h, c);
  if (use_imgb)
    k_encproj<0><<<416, 256, 0, stream>>>(imgb, img, Wencb, Wenc, benc, epj);
  else
    k_encproj<1><<<416, 256, 0, stream>>>(imgb, img, Wencb, Wenc, benc, epj);
  // U_h + gate for step 0 (+ h0 -> x staging)
  k_hcons<<<40, 256, 0, stream>>>(h, Wdecb, bdec, Wgateb, bgate, uh, gate, x);
  for (int t = 0; t < TT; ++t) {
    k_escore<<<dim3(BB, 4), 256, 0, stream>>>(uh, epj, Wfin, bfin, cap, emb, e_ws, x, t);
    if (use_imgb)
      k_ctx<0><<<dim3(BB, 4), 256, 0, stream>>>(e_ws, gate, imgb, img, x, alphas, t);
    else
      k_ctx<1><<<dim3(BB, 4), 256, 0, stream>>>(e_ws, gate, imgb, img, x, alphas, t);
    k_lstm_part<<<dim3(32, 4), 256, 0, stream>>>(x, Wcomb, pbuf);
    k_lstm_fin<<<32, 256, 0, stream>>>(pbuf, bih, bhh, c, h, hall, t);
    if (t + 1 < TT)
      k_hcons<<<40, 256, 0, stream>>>(h, Wdecb, bdec, Wgateb, bgate, uh, gate, x);
  }
  k_logits<<<dim3(10, 79), 256, 0, stream>>>(hall, Woutb2, bout, preds);
}